// Round 8
// baseline (654.708 us; speedup 1.0000x reference)
//
#include <hip/hip_runtime.h>
#include <math.h>

#define NSWEEP 6
#define NR (NSWEEP * 63)

// ---------------------------------------------------------------------------
// Kernel 1: partial max-pooled outer products. Grid = B*G blocks.
// ---------------------------------------------------------------------------
__global__ __launch_bounds__(256) void pool_kernel(const float* __restrict__ x,
                                                   float* __restrict__ part,
                                                   int G) {
  __shared__ float xs[4096];
  const int t = threadIdx.x;
  const int blk = blockIdx.x;
  const int b = blk / G, g = blk % G;
  const int npb = 4096 / G;
  const int ntile = npb >> 6;
  const int n0 = g * npb;
  const int i0 = (t >> 4) * 4;
  const int j0 = (t & 15) * 4;

  float mv[4][4];
#pragma unroll
  for (int a = 0; a < 4; ++a)
#pragma unroll
    for (int c = 0; c < 4; ++c) mv[a][c] = -INFINITY;

  const float4* src = reinterpret_cast<const float4*>(x + ((size_t)b * 4096 + n0) * 64);
  float4* xs4 = reinterpret_cast<float4*>(xs);

  for (int tile = 0; tile < ntile; ++tile) {
#pragma unroll
    for (int q = 0; q < 4; ++q) xs4[t + 256 * q] = src[(size_t)tile * 1024 + t + 256 * q];
    __syncthreads();
#pragma unroll 4
    for (int n = 0; n < 64; ++n) {
      const float4 vi = *reinterpret_cast<const float4*>(&xs[n * 64 + i0]);
      const float4 vj = *reinterpret_cast<const float4*>(&xs[n * 64 + j0]);
      const float fi[4] = {vi.x, vi.y, vi.z, vi.w};
      const float fj[4] = {vj.x, vj.y, vj.z, vj.w};
#pragma unroll
      for (int a = 0; a < 4; ++a)
#pragma unroll
        for (int c = 0; c < 4; ++c)
          mv[a][c] = fmaxf(mv[a][c], fi[a] * fj[c]);
    }
    __syncthreads();
  }

#pragma unroll
  for (int a = 0; a < 4; ++a)
#pragma unroll
    for (int c = 0; c < 4; ++c)
      xs[(i0 + a) * 64 + (j0 + c)] = mv[a][c];
  __syncthreads();

  float* dst = part + ((size_t)b * G + g) * 4096;
#pragma unroll
  for (int q = 0; q < 16; ++q) dst[t + 256 * q] = xs[t + 256 * q];
}

// ---------------------------------------------------------------------------
// Kernel 2: grid 8, block 256; each block owns TWO batches.
//   wave0: 2-batch interleaved Jacobi producer (B's VALU fills A's DS stalls)
//   wave1: V consumer batch A (LDS ring replay)   wave2: V consumer batch B
//   wave3: parks; all 4 waves do the R = W*V^T epilogue (2 waves per batch).
// ---------------------------------------------------------------------------
__device__ __forceinline__ float bperm(int byteaddr, float v) {
  return __int_as_float(__builtin_amdgcn_ds_bpermute(byteaddr, __float_as_int(v)));
}

__device__ __forceinline__ int partner_of(int lane, int r) {
  if (lane == 0) { int q = 62 + r; if (q >= 63) q -= 63; return 1 + q; }
  int u = lane - 1 - r; if (u < 0) u += 63;
  if (u == 62) return 0;
  int m = 61 - u + r; if (m >= 63) m -= 63; return 1 + m;
}

#define DOT64(dst, g, ex)                                                     \
  {                                                                           \
    float d0_ = 0, d1_ = 0, d2_ = 0, d3_ = 0;                                 \
    _Pragma("unroll") for (int k_ = 0; k_ < 64; k_ += 4) {                    \
      d0_ = fmaf(g[k_], ex[k_], d0_);                                         \
      d1_ = fmaf(g[k_ + 1], ex[k_ + 1], d1_);                                 \
      d2_ = fmaf(g[k_ + 2], ex[k_ + 2], d2_);                                 \
      d3_ = fmaf(g[k_ + 3], ex[k_ + 3], d3_);                                 \
    }                                                                         \
    dst = (d0_ + d1_) + (d2_ + d3_);                                          \
  }

#define NORM64(dst, g)                                                        \
  {                                                                           \
    float n0_ = 0, n1_ = 0, n2_ = 0, n3_ = 0;                                 \
    _Pragma("unroll") for (int k_ = 0; k_ < 64; k_ += 4) {                    \
      n0_ = fmaf(g[k_], g[k_], n0_);                                          \
      n1_ = fmaf(g[k_ + 1], g[k_ + 1], n1_);                                  \
      n2_ = fmaf(g[k_ + 2], g[k_ + 2], n2_);                                  \
      n3_ = fmaf(g[k_ + 3], g[k_ + 3], n3_);                                  \
    }                                                                         \
    dst = (n0_ + n1_) + (n2_ + n3_);                                          \
  }

// (c,s) bitwise pair-consistent: u negates exactly on partner; tie by role.
#define ANGLE(aX, bbX, dX, roleSgn, cX, sX)                                   \
  {                                                                           \
    const float u_ = (bbX - aX) * 0.5f;                                       \
    const float sg_ = (u_ != 0.0f) ? copysignf(1.0f, u_) : roleSgn;           \
    const float h_ = sqrtf(fmaf(u_, u_, dX * dX));                            \
    const float tt_ = (dX == 0.0f)                                            \
        ? 0.0f : dX * sg_ * __builtin_amdgcn_rcpf(fabsf(u_) + h_);            \
    cX = rsqrtf(fmaf(tt_, tt_, 1.0f));                                        \
    sX = tt_ * cX;                                                            \
  }

__global__ __launch_bounds__(256, 1) void svd_kernel(const float* __restrict__ part,
                                                     float* __restrict__ out, int G) {
  __shared__ __align__(16) float WA[64 * 68];   // pooled A -> W_A -> R_A
  __shared__ __align__(16) float WB[64 * 68];
  __shared__ __align__(16) float VA[64 * 68];
  __shared__ __align__(16) float VB[64 * 68];
  __shared__ float2 ringA[64][64];
  __shared__ float2 ringB[64][64];
  __shared__ float red[4];
  __shared__ int pflag, cflagA, cflagB;

  const int blk = blockIdx.x;            // 0..7
  const int bA = blk * 2, bB = blk * 2 + 1;
  const int t = threadIdx.x;
  const int wave = t >> 6, lane = t & 63;

  if (t == 0) { pflag = 0; cflagA = 0; cflagB = 0; }

  // ---- prologue: max-reduce partials for both batches (all 256 threads) ----
  {
    const float4* pa = reinterpret_cast<const float4*>(part) + (size_t)bA * G * 1024;
    const float4* pb = reinterpret_cast<const float4*>(part) + (size_t)bB * G * 1024;
    float4 accA[4], accB[4];
#pragma unroll
    for (int u = 0; u < 4; ++u) { accA[u] = pa[t + 256 * u]; accB[u] = pb[t + 256 * u]; }
    for (int g = 1; g < G; ++g) {
#pragma unroll
      for (int u = 0; u < 4; ++u) {
        const float4 va = pa[(size_t)g * 1024 + t + 256 * u];
        const float4 vb = pb[(size_t)g * 1024 + t + 256 * u];
        accA[u].x = fmaxf(accA[u].x, va.x); accA[u].y = fmaxf(accA[u].y, va.y);
        accA[u].z = fmaxf(accA[u].z, va.z); accA[u].w = fmaxf(accA[u].w, va.w);
        accB[u].x = fmaxf(accB[u].x, vb.x); accB[u].y = fmaxf(accB[u].y, vb.y);
        accB[u].z = fmaxf(accB[u].z, vb.z); accB[u].w = fmaxf(accB[u].w, vb.w);
      }
    }
#pragma unroll
    for (int u = 0; u < 4; ++u) {
      const int idx = t + 256 * u;
      const int i = idx >> 4, j = (idx & 15) * 4;
      *reinterpret_cast<float4*>(&WA[i * 68 + j]) = accA[u];
      *reinterpret_cast<float4*>(&WB[i * 68 + j]) = accB[u];
    }
  }
  __syncthreads();

  if (wave == 0) {
    // ============ producer: two interleaved Jacobi chains ============
    float gA[64], gB[64], exA[64], exB[64];
#pragma unroll
    for (int k = 0; k < 64; ++k) { gA[k] = WA[k * 68 + lane]; gB[k] = WB[k * 68 + lane]; }

    float aA, aB;
    NORM64(aA, gA);
    NORM64(aB, gB);

    int rr = 0;
    int partner = partner_of(lane, 0);
    int addr = partner << 2;
#pragma unroll
    for (int k = 0; k < 64; ++k) exA[k] = bperm(addr, gA[k]);
    float bbA = bperm(addr, aA);
#pragma unroll
    for (int k = 0; k < 64; ++k) exB[k] = bperm(addr, gB[k]);
    float bbB = bperm(addr, aB);

#pragma unroll 1
    for (int rg = 0; rg < NR; ++rg) {
      const float roleSgn = (lane < partner) ? 1.0f : -1.0f;

      float dA, dB;
      DOT64(dA, gA, exA);
      DOT64(dB, gB, exB);

      float cA, sA, cB, sB;
      ANGLE(aA, bbA, dA, roleSgn, cA, sA);   // two independent chains: ILP
      ANGLE(aB, bbB, dB, roleSgn, cB, sB);

      ringA[rg & 63][lane] = make_float2(cA, sA);
      ringB[rg & 63][lane] = make_float2(cB, sB);
      if ((rg & 15) == 15) {
        if (lane == 0)
          __hip_atomic_store(&pflag, rg + 1, __ATOMIC_RELEASE, __HIP_MEMORY_SCOPE_WORKGROUP);
        int cd = min(__hip_atomic_load(&cflagA, __ATOMIC_ACQUIRE, __HIP_MEMORY_SCOPE_WORKGROUP),
                     __hip_atomic_load(&cflagB, __ATOMIC_ACQUIRE, __HIP_MEMORY_SCOPE_WORKGROUP));
        while (rg + 1 - cd > 40) {
          __builtin_amdgcn_s_sleep(2);
          cd = min(__hip_atomic_load(&cflagA, __ATOMIC_ACQUIRE, __HIP_MEMORY_SCOPE_WORKGROUP),
                   __hip_atomic_load(&cflagB, __ATOMIC_ACQUIRE, __HIP_MEMORY_SCOPE_WORKGROUP));
        }
      }

      rr = (rr == 62) ? 0 : rr + 1;
      partner = partner_of(lane, rr);
      addr = partner << 2;

      const float nsA = -sA;
#pragma unroll
      for (int k = 0; k < 64; ++k) {
        gA[k] = fmaf(nsA, exA[k], cA * gA[k]);
        exA[k] = bperm(addr, gA[k]);
      }
      if (rr == 0) { NORM64(aA, gA); }
      else aA = fmaf(cA * cA, aA, fmaf(sA * sA, bbA, -2.0f * (cA * sA) * dA));
      bbA = bperm(addr, aA);

      const float nsB = -sB;
#pragma unroll
      for (int k = 0; k < 64; ++k) {
        gB[k] = fmaf(nsB, exB[k], cB * gB[k]);
        exB[k] = bperm(addr, gB[k]);
      }
      if (rr == 0) { NORM64(aB, gB); }
      else aB = fmaf(cB * cB, aB, fmaf(sB * sB, bbB, -2.0f * (cB * sB) * dB));
      bbB = bperm(addr, aB);
    }
    if (lane == 0)
      __hip_atomic_store(&pflag, NR, __ATOMIC_RELEASE, __HIP_MEMORY_SCOPE_WORKGROUP);

    // exact sigma; W = G * diag(sigma^{-1/2}) into WA/WB
    float s2A, s2B;
    NORM64(s2A, gA);
    NORM64(s2B, gB);
    const float sgA = sqrtf(s2A), sgB = sqrtf(s2B);
    const float cfA = (sgA > 1e-30f) ? rsqrtf(sgA) : 0.0f;
    const float cfB = (sgB > 1e-30f) ? rsqrtf(sgB) : 0.0f;
#pragma unroll
    for (int k = 0; k < 64; ++k) {
      WA[k * 68 + lane] = gA[k] * cfA;
      WB[k * 68 + lane] = gB[k] * cfB;
    }

  } else if (wave == 1 || wave == 2) {
    // ============ consumers: V replay from LDS ring ============
    float2 (*rng)[64] = (wave == 1) ? ringA : ringB;
    int* cfl = (wave == 1) ? &cflagA : &cflagB;
    float* Vl = (wave == 1) ? VA : VB;

    float v[64], ex[64];
#pragma unroll
    for (int k = 0; k < 64; ++k) v[k] = (k == lane) ? 1.0f : 0.0f;

    int rr = 0;
    int partner = partner_of(lane, 0);
    int addr = partner << 2;
#pragma unroll
    for (int k = 0; k < 64; ++k) ex[k] = bperm(addr, v[k]);

    int seen = 0;
#pragma unroll 1
    for (int rg = 0; rg < NR; ++rg) {
      if (seen < rg + 1) {
        for (;;) {
          seen = __hip_atomic_load(&pflag, __ATOMIC_ACQUIRE, __HIP_MEMORY_SCOPE_WORKGROUP);
          if (seen >= rg + 1) break;
          __builtin_amdgcn_s_sleep(2);
        }
      }
      const float2 cs = rng[rg & 63][lane];
      const float c = cs.x, ns = -cs.y;

      rr = (rr == 62) ? 0 : rr + 1;
      partner = partner_of(lane, rr);
      addr = partner << 2;

#pragma unroll
      for (int k = 0; k < 64; ++k) {
        v[k] = fmaf(ns, ex[k], c * v[k]);
        ex[k] = bperm(addr, v[k]);
      }
      if ((rg & 15) == 15 && lane == 0)
        __hip_atomic_store(cfl, rg + 1, __ATOMIC_RELEASE, __HIP_MEMORY_SCOPE_WORKGROUP);
    }
#pragma unroll
    for (int k = 0; k < 64; ++k) Vl[k * 68 + lane] = v[k];
  }
  // wave 3 parks here
  __syncthreads();

  // ---- epilogue: waves 0,1 -> batch A; waves 2,3 -> batch B ----
  const int half = wave >> 1;
  float* Wl = half ? WB : WA;
  float* Vl = half ? VB : VA;
  const int j0 = (wave & 1) * 32;

  float wr[64];
#pragma unroll
  for (int jb = 0; jb < 16; ++jb) {
    const float4 v4 = *reinterpret_cast<const float4*>(&Wl[lane * 68 + jb * 4]);
    wr[4 * jb] = v4.x; wr[4 * jb + 1] = v4.y; wr[4 * jb + 2] = v4.z; wr[4 * jb + 3] = v4.w;
  }
  __syncthreads();  // snapshots taken; W rows free for R

  float rvals[32];
  float ssq = 0.0f;
#pragma unroll 4
  for (int jj = 0; jj < 32; ++jj) {
    const float4* vr = reinterpret_cast<const float4*>(&Vl[(j0 + jj) * 68]);
    float c0 = 0, c1 = 0, c2 = 0, c3 = 0;
#pragma unroll
    for (int kb = 0; kb < 16; ++kb) {
      const float4 vv = vr[kb];   // broadcast: conflict-free
      c0 = fmaf(wr[4 * kb], vv.x, c0);
      c1 = fmaf(wr[4 * kb + 1], vv.y, c1);
      c2 = fmaf(wr[4 * kb + 2], vv.z, c2);
      c3 = fmaf(wr[4 * kb + 3], vv.w, c3);
    }
    const float accv = (c0 + c1) + (c2 + c3);  // R[lane][j0+jj]
    rvals[jj] = accv;
    ssq = fmaf(accv, accv, ssq);
  }
#pragma unroll
  for (int jj = 0; jj < 8; ++jj)
    *reinterpret_cast<float4*>(&Wl[lane * 68 + j0 + 4 * jj]) =
        make_float4(rvals[4 * jj], rvals[4 * jj + 1], rvals[4 * jj + 2], rvals[4 * jj + 3]);

#pragma unroll
  for (int off = 32; off; off >>= 1) ssq += __shfl_xor(ssq, off, 64);
  if (lane == 0) red[wave] = ssq;
  __syncthreads();

  const float rn = half ? rsqrtf(fmaxf(red[2] + red[3], 1e-24f))
                        : rsqrtf(fmaxf(red[0] + red[1], 1e-24f));
  const int batch = blk * 2 + half;
  const int t128 = t & 127;
  float* o = out + (size_t)batch * 4096;
#pragma unroll
  for (int u = 0; u < 32; ++u) {
    const int e = t128 + 128 * u;
    o[e] = Wl[(e >> 6) * 68 + (e & 63)] * rn;
  }
}

extern "C" void kernel_launch(void* const* d_in, const int* in_sizes, int n_in,
                              void* d_out, int out_size, void* d_ws, size_t ws_size,
                              hipStream_t stream) {
  const float* x = (const float*)d_in[0];
  float* out = (float*)d_out;
  float* part = (float*)d_ws;

  int G = 16;
  while (G > 1 && (size_t)16 * G * 4096 * 4 > ws_size) G >>= 1;

  pool_kernel<<<dim3(16 * G), dim3(256), 0, stream>>>(x, part, G);
  svd_kernel<<<dim3(8), dim3(256), 0, stream>>>(part, out, G);
}